// Round 5
// baseline (370.591 us; speedup 1.0000x reference)
//
#include <hip/hip_runtime.h>
#include <math.h>

#define NQ 1024
#define NR 100000
#define D  128
#define K  8
#define TR 32
#define NTILES 3125            // NR / TR exactly (100000 = 3125*32)
#define NCH 125                // ref chunks (main path)
#define TPC 25                 // tiles per chunk = NTILES / NCH
#define NQG 2                  // query groups of 512

typedef __attribute__((ext_vector_type(8))) short short8;
typedef __attribute__((ext_vector_type(4))) float f32x4;
typedef unsigned int u32;
typedef __attribute__((address_space(1))) const u32 gu32;
typedef __attribute__((address_space(3))) u32 lu32;

static __device__ __forceinline__ unsigned short f2bf(float f) {
    unsigned int u = __float_as_uint(f);            // RTNE f32 -> bf16
    return (unsigned short)((u + 0x7FFFu + ((u >> 16) & 1u)) >> 16);
}
static __device__ __forceinline__ float bf2f(unsigned short h) {
    return __uint_as_float(((unsigned int)h) << 16);
}

// sorted-ascending top-K(smallest) insert, branch-guarded (rare after warmup)
__device__ __forceinline__ void topk_insert(float (&t)[K], float d) {
    if (d < t[K - 1]) {
#pragma unroll
        for (int j = K - 1; j > 0; --j)
            t[j] = (d >= t[j]) ? t[j] : ((d < t[j - 1]) ? t[j - 1] : d);
        t[0] = (d < t[0]) ? d : t[0];
    }
}

// =====================  FAST PATH  =====================

// ---- prepass: base f32 -> tile-major swizzled bf16 hi/lo + f32 row norms ----
// Tile t holds rows [t*32, t*32+32); within a tile, row r's dims c*8..c*8+7 land
// at shorts idx = r*128 + 8*(c ^ (r&15))  (XOR slot swizzle; matches main reads).
__global__ __launch_bounds__(512, 4) void knn_prep(const float* __restrict__ base,
                                                   unsigned short* __restrict__ bhi,
                                                   unsigned short* __restrict__ blo,
                                                   float* __restrict__ bn) {
    const int t   = blockIdx.x;
    const int tid = threadIdx.x;
    const int r   = tid >> 4;          // 0..31
    const int c   = tid & 15;          // dim group
    const int row = t * TR + r;

    const float4 a = *(const float4*)(base + (size_t)row * D + c * 8);
    const float4 b = *(const float4*)(base + (size_t)row * D + c * 8 + 4);
    float v[8] = {a.x, a.y, a.z, a.w, b.x, b.y, b.z, b.w};
    float s2 = 0.f;
    short8 hh, ll;
#pragma unroll
    for (int j = 0; j < 8; ++j) {
        s2 = fmaf(v[j], v[j], s2);
        const unsigned short h = f2bf(v[j]);
        const float res = v[j] - bf2f(h);           // exact residual
        hh[j] = (short)h;
        ll[j] = (short)f2bf(res);
    }
    // row norm: reduce across the 16 lanes (c) sharing this row
    s2 += __shfl_xor(s2, 1, 64);
    s2 += __shfl_xor(s2, 2, 64);
    s2 += __shfl_xor(s2, 4, 64);
    s2 += __shfl_xor(s2, 8, 64);

    const size_t o = (size_t)t * (TR * 128) + r * 128 + 8 * (c ^ (r & 15));
    *(short8*)(bhi + o) = hh;
    *(short8*)(blo + o) = ll;
    if (c == 0) bn[row] = s2;
}

// ---- main: MFMA distances + per-chunk top-8 ----
// grid = 2 q-groups x 125 chunks = 250 blocks (1/CU); 512 thr (8 waves).
// Each wave: 64 queries (4 q-tiles) as -2-scaled hi/lo bf16 B-frags in regs.
// Refs staged via global_load_lds from the pre-swizzled ws arrays (zero VALU).
// 3-term split: a.b ~= ah.bh + ah.bl + al.bh. Per (rt,s): 2KB LDS -> 12 MFMA
// = 96 flop/B vs 39.7 balance -> MFMA-bound 2.4x. Prefetch-before-compute,
// one barrier/tile (m97 pattern): loads drain under the ~3700cy MFMA phase.
__global__ __launch_bounds__(512, 2) void knn_mfma2(const float* __restrict__ x,
                                                    const unsigned short* __restrict__ bhi,
                                                    const unsigned short* __restrict__ blo,
                                                    const float* __restrict__ bn,
                                                    float* __restrict__ cand) {
    __shared__ unsigned short lhs[2][TR * 128];   // 8KB per buf
    __shared__ unsigned short lls[2][TR * 128];

    const int tid  = threadIdx.x;
    const int lane = tid & 63;
    const int w    = tid >> 6;          // wave 0..7
    const int lm   = lane & 15;
    const int kg   = lane >> 4;         // k-group 0..3
    const int qb   = blockIdx.x & 1;
    const int rc   = blockIdx.x >> 1;   // 0..124
    const int t0   = rc * TPC;

    // ---- B-frags: 64 queries/wave, scaled -2, split hi/lo ----
    short8 Bh[4][4], Bl[4][4];
    float  xn[4];
#pragma unroll
    for (int qt = 0; qt < 4; ++qt) {
        const int q = qb * 512 + w * 64 + qt * 16 + lm;
        float s2 = 0.f;
#pragma unroll
        for (int s = 0; s < 4; ++s) {
            const float4 a = *(const float4*)(x + (size_t)q * D + s * 32 + kg * 8);
            const float4 b = *(const float4*)(x + (size_t)q * D + s * 32 + kg * 8 + 4);
            float v[8] = {a.x, a.y, a.z, a.w, b.x, b.y, b.z, b.w};
            short8 hh, ll;
#pragma unroll
            for (int j = 0; j < 8; ++j) {
                s2 = fmaf(v[j], v[j], s2);
                const float m2 = -2.f * v[j];
                const unsigned short h = f2bf(m2);
                const float res = m2 - bf2f(h);
                hh[j] = (short)h;
                ll[j] = (short)f2bf(res);
            }
            Bh[qt][s] = hh; Bl[qt][s] = ll;
        }
        s2 += __shfl_xor(s2, 16, 64);
        s2 += __shfl_xor(s2, 32, 64);
        xn[qt] = s2;
    }

    // ---- async stage: 16KB/tile, 1 hi + 1 lo load per thread ----
    auto stage = [&](int ti, int buf) {
        const size_t gb = (size_t)(t0 + ti) * (TR * 128);
        unsigned short* lh = &lhs[buf][w * 512];              // wave-uniform LDS base
        unsigned short* ll = &lls[buf][w * 512];
        const unsigned short* gh = bhi + gb + w * 512 + lane * 8;   // per-lane source
        const unsigned short* gl = blo + gb + w * 512 + lane * 8;
        __builtin_amdgcn_global_load_lds((gu32*)gh, (lu32*)lh, 16, 0, 0);
        __builtin_amdgcn_global_load_lds((gu32*)gl, (lu32*)ll, 16, 0, 0);
    };

    float tk[4][K];
#pragma unroll
    for (int qt = 0; qt < 4; ++qt)
#pragma unroll
        for (int j = 0; j < K; ++j) tk[qt][j] = INFINITY;

    stage(0, 0);
    __syncthreads();                    // drains vmcnt, tile 0 ready

    int cur = 0;
    for (int ti = 0; ti < TPC; ++ti) {
        if (ti + 1 < TPC) stage(ti + 1, cur ^ 1);   // in flight across compute

#pragma unroll
        for (int rt = 0; rt < 2; ++rt) {
            const f32x4 bn4 = *(const f32x4*)(bn + (size_t)(t0 + ti) * TR + rt * 16 + kg * 4);
            f32x4 acc[4];
#pragma unroll
            for (int qt = 0; qt < 4; ++qt) acc[qt] = (f32x4){0.f, 0.f, 0.f, 0.f};
#pragma unroll
            for (int s = 0; s < 4; ++s) {
                const int idx = (rt * 16 + lm) * 128 + 8 * ((s * 4 + kg) ^ lm);
                const short8 Ah = *(const short8*)&lhs[cur][idx];
                const short8 Al = *(const short8*)&lls[cur][idx];
#pragma unroll
                for (int qt = 0; qt < 4; ++qt) {
                    acc[qt] = __builtin_amdgcn_mfma_f32_16x16x32_bf16(Ah, Bh[qt][s], acc[qt], 0, 0, 0);
                    acc[qt] = __builtin_amdgcn_mfma_f32_16x16x32_bf16(Ah, Bl[qt][s], acc[qt], 0, 0, 0);
                    acc[qt] = __builtin_amdgcn_mfma_f32_16x16x32_bf16(Al, Bh[qt][s], acc[qt], 0, 0, 0);
                }
            }
#pragma unroll
            for (int qt = 0; qt < 4; ++qt)
#pragma unroll
                for (int j = 0; j < 4; ++j) topk_insert(tk[qt], acc[qt][j] + bn4[j]);
        }

        __syncthreads();                // prefetch drained, all waves done reading
        cur ^= 1;
    }

    // ---- merge the 4 k-group lanes holding the same query ----
#pragma unroll
    for (int st = 16; st <= 32; st <<= 1) {
#pragma unroll
        for (int qt = 0; qt < 4; ++qt) {
            float o[K];
#pragma unroll
            for (int j = 0; j < K; ++j) o[j] = __shfl_xor(tk[qt][j], st, 64);
#pragma unroll
            for (int j = 0; j < K; ++j) topk_insert(tk[qt], o[j]);
        }
    }

    if (kg == 0) {
#pragma unroll
        for (int qt = 0; qt < 4; ++qt) {
            const int q = qb * 512 + w * 64 + qt * 16 + lm;
            float* cp = cand + ((size_t)q * NCH + rc) * K;
#pragma unroll
            for (int j = 0; j < K; ++j)
                cp[j] = sqrtf(fmaxf(tk[qt][j] + xn[qt], 0.f));
        }
    }
}

// ---- merge 125 per-chunk top-8s per query (already sqrt'd) ----
__global__ __launch_bounds__(256, 4) void knn_merge2(const float* __restrict__ cand,
                                                     float* __restrict__ out) {
    const int q = blockIdx.x * blockDim.x + threadIdx.x;
    if (q >= NQ) return;
    const float* cp = cand + (size_t)q * (NCH * K);
    float t[K];
#pragma unroll
    for (int j = 0; j < K; ++j) t[j] = INFINITY;
    for (int i = 0; i < NCH * K; i += 4) {
        const float4 v = *(const float4*)(cp + i);
        topk_insert(t, v.x); topk_insert(t, v.y);
        topk_insert(t, v.z); topk_insert(t, v.w);
    }
#pragma unroll
    for (int j = 0; j < K; ++j) out[(size_t)q * K + j] = t[j];
}

// =====================  FALLBACK (round-4 proven, if ws too small)  ==========
#define FB_NCH   64
#define FB_CHUNK 1563
#define FB_NT    49

__global__ __launch_bounds__(512, 2) void knn_mfma_fb(const float* __restrict__ x,
                                                      const float* __restrict__ base,
                                                      float* __restrict__ cand) {
    __shared__ unsigned short lhs[2][TR * 128];
    __shared__ unsigned short lls[2][TR * 128];
    __shared__ float lbn[2][TR];

    const int tid  = threadIdx.x;
    const int lane = tid & 63;
    const int w    = tid >> 6;
    const int lm   = lane & 15;
    const int kg   = lane >> 4;
    const int qb   = blockIdx.x & 3;
    const int rc   = blockIdx.x >> 2;
    const int r0   = rc * FB_CHUNK;
    const int rend = (r0 + FB_CHUNK < NR) ? (r0 + FB_CHUNK) : NR;

    short8 Bh[2][4], Bl[2][4];
    float  xn[2];
#pragma unroll
    for (int qt = 0; qt < 2; ++qt) {
        const int q = qb * 256 + w * 32 + qt * 16 + lm;
        float s2 = 0.f;
#pragma unroll
        for (int s = 0; s < 4; ++s) {
            const float4 a = *(const float4*)(x + (size_t)q * D + s * 32 + kg * 8);
            const float4 b = *(const float4*)(x + (size_t)q * D + s * 32 + kg * 8 + 4);
            float v[8] = {a.x, a.y, a.z, a.w, b.x, b.y, b.z, b.w};
            short8 hh, ll;
#pragma unroll
            for (int j = 0; j < 8; ++j) {
                s2 = fmaf(v[j], v[j], s2);
                const float m2 = -2.f * v[j];
                const unsigned short h = f2bf(m2);
                const float res = m2 - bf2f(h);
                hh[j] = (short)h;
                ll[j] = (short)f2bf(res);
            }
            Bh[qt][s] = hh; Bl[qt][s] = ll;
        }
        s2 += __shfl_xor(s2, 16, 64);
        s2 += __shfl_xor(s2, 32, 64);
        xn[qt] = s2;
    }

    const int srow = tid >> 4;
    const int scol = tid & 15;

    auto convert_store = [&](const float (&v)[8], int gr, int buf) {
        float s2 = 0.f;
        short8 hh, ll;
#pragma unroll
        for (int j = 0; j < 8; ++j) {
            s2 = fmaf(v[j], v[j], s2);
            const unsigned short h = f2bf(v[j]);
            const float res = v[j] - bf2f(h);
            hh[j] = (short)h;
            ll[j] = (short)f2bf(res);
        }
        s2 += __shfl_xor(s2, 1, 64);
        s2 += __shfl_xor(s2, 2, 64);
        s2 += __shfl_xor(s2, 4, 64);
        s2 += __shfl_xor(s2, 8, 64);
        const int idx = srow * 128 + 8 * (scol ^ (srow & 15));
        *(short8*)&lhs[buf][idx] = hh;
        *(short8*)&lls[buf][idx] = ll;
        if (scol == 0) lbn[buf][srow] = (gr < rend) ? s2 : INFINITY;
    };

    {
        const int gr = r0 + srow;
        float v[8] = {0, 0, 0, 0, 0, 0, 0, 0};
        if (gr < NR) {
            const float4 a = *(const float4*)(base + (size_t)gr * D + scol * 8);
            const float4 b = *(const float4*)(base + (size_t)gr * D + scol * 8 + 4);
            v[0] = a.x; v[1] = a.y; v[2] = a.z; v[3] = a.w;
            v[4] = b.x; v[5] = b.y; v[6] = b.z; v[7] = b.w;
        }
        convert_store(v, gr, 0);
    }
    __syncthreads();

    float t0a[K], t1a[K];
#pragma unroll
    for (int j = 0; j < K; ++j) { t0a[j] = INFINITY; t1a[j] = INFINITY; }

    int cur = 0;
    for (int ti = 0; ti < FB_NT; ++ti) {
        float pv[8] = {0, 0, 0, 0, 0, 0, 0, 0};
        int pgr = NR;
        if (ti + 1 < FB_NT) {
            pgr = r0 + (ti + 1) * TR + srow;
            if (pgr < NR) {
                const float4 a = *(const float4*)(base + (size_t)pgr * D + scol * 8);
                const float4 b = *(const float4*)(base + (size_t)pgr * D + scol * 8 + 4);
                pv[0] = a.x; pv[1] = a.y; pv[2] = a.z; pv[3] = a.w;
                pv[4] = b.x; pv[5] = b.y; pv[6] = b.z; pv[7] = b.w;
            }
        }

#pragma unroll
        for (int rt = 0; rt < 2; ++rt) {
            const f32x4 bn4 = *(const f32x4*)&lbn[cur][rt * 16 + kg * 4];
            f32x4 acc0 = {0.f, 0.f, 0.f, 0.f};
            f32x4 acc1 = {0.f, 0.f, 0.f, 0.f};
#pragma unroll
            for (int s = 0; s < 4; ++s) {
                const int idx = (rt * 16 + lm) * 128 + 8 * ((s * 4 + kg) ^ lm);
                const short8 Ah = *(const short8*)&lhs[cur][idx];
                const short8 Al = *(const short8*)&lls[cur][idx];
                acc0 = __builtin_amdgcn_mfma_f32_16x16x32_bf16(Ah, Bh[0][s], acc0, 0, 0, 0);
                acc1 = __builtin_amdgcn_mfma_f32_16x16x32_bf16(Ah, Bh[1][s], acc1, 0, 0, 0);
                acc0 = __builtin_amdgcn_mfma_f32_16x16x32_bf16(Ah, Bl[0][s], acc0, 0, 0, 0);
                acc1 = __builtin_amdgcn_mfma_f32_16x16x32_bf16(Ah, Bl[1][s], acc1, 0, 0, 0);
                acc0 = __builtin_amdgcn_mfma_f32_16x16x32_bf16(Al, Bh[0][s], acc0, 0, 0, 0);
                acc1 = __builtin_amdgcn_mfma_f32_16x16x32_bf16(Al, Bh[1][s], acc1, 0, 0, 0);
            }
#pragma unroll
            for (int j = 0; j < 4; ++j) {
                topk_insert(t0a, acc0[j] + bn4[j]);
                topk_insert(t1a, acc1[j] + bn4[j]);
            }
        }

        if (ti + 1 < FB_NT) convert_store(pv, pgr, cur ^ 1);
        __syncthreads();
        cur ^= 1;
    }

#pragma unroll
    for (int st = 16; st <= 32; st <<= 1) {
        float o0[K], o1[K];
#pragma unroll
        for (int j = 0; j < K; ++j) {
            o0[j] = __shfl_xor(t0a[j], st, 64);
            o1[j] = __shfl_xor(t1a[j], st, 64);
        }
#pragma unroll
        for (int j = 0; j < K; ++j) { topk_insert(t0a, o0[j]); topk_insert(t1a, o1[j]); }
    }

    if (kg == 0) {
#pragma unroll
        for (int qt = 0; qt < 2; ++qt) {
            const int q = qb * 256 + w * 32 + qt * 16 + lm;
            float* cp = cand + ((size_t)q * FB_NCH + rc) * K;
#pragma unroll
            for (int j = 0; j < K; ++j) {
                const float d2 = (qt ? t1a[j] : t0a[j]) + xn[qt];
                cp[j] = sqrtf(fmaxf(d2, 0.f));
            }
        }
    }
}

__global__ __launch_bounds__(256, 4) void knn_merge_fb(const float* __restrict__ cand,
                                                       float* __restrict__ out) {
    const int q = blockIdx.x * blockDim.x + threadIdx.x;
    if (q >= NQ) return;
    const float* cp = cand + (size_t)q * (FB_NCH * K);
    float t[K];
#pragma unroll
    for (int j = 0; j < K; ++j) t[j] = INFINITY;
    for (int i = 0; i < FB_NCH * K; i += 4) {
        const float4 v = *(const float4*)(cp + i);
        topk_insert(t, v.x); topk_insert(t, v.y);
        topk_insert(t, v.z); topk_insert(t, v.w);
    }
#pragma unroll
    for (int j = 0; j < K; ++j) out[(size_t)q * K + j] = t[j];
}

// =============================================================================
extern "C" void kernel_launch(void* const* d_in, const int* in_sizes, int n_in,
                              void* d_out, int out_size, void* d_ws, size_t ws_size,
                              hipStream_t stream) {
    const float* x    = (const float*)d_in[0];
    const float* base = (const float*)d_in[1];
    float* out = (float*)d_out;

    // ws layout (fast path): bhi 25.6MB | blo 25.6MB | bn 400KB | cand 4MB
    const size_t OFF_BLO  = 25600000;       // NTILES*4096*2
    const size_t OFF_BN   = 51200000;
    const size_t OFF_CAND = 51600384;       // 512-aligned
    const size_t NEED     = OFF_CAND + (size_t)NQ * NCH * K * 4;   // 55,696,384

    if (ws_size >= NEED) {
        unsigned short* bhi = (unsigned short*)d_ws;
        unsigned short* blo = (unsigned short*)((char*)d_ws + OFF_BLO);
        float* bn   = (float*)((char*)d_ws + OFF_BN);
        float* cand = (float*)((char*)d_ws + OFF_CAND);

        knn_prep<<<NTILES, 512, 0, stream>>>(base, bhi, blo, bn);
        knn_mfma2<<<NQG * NCH, 512, 0, stream>>>(x, bhi, blo, bn, cand);
        knn_merge2<<<(NQ + 255) / 256, 256, 0, stream>>>(cand, out);
    } else {
        float* cand = (float*)d_ws;         // 2MB, round-4 proven path
        knn_mfma_fb<<<4 * FB_NCH, 512, 0, stream>>>(x, base, cand);
        knn_merge_fb<<<(NQ + 255) / 256, 256, 0, stream>>>(cand, out);
    }
}

// Round 6
// 348.207 us; speedup vs baseline: 1.0643x; 1.0643x over previous
//
#include <hip/hip_runtime.h>
#include <math.h>

#define NQ 1024
#define NR 100000
#define D  128
#define K  8
#define TR 32
#define NCH   125            // ref chunks
#define CHUNK 800            // rows per chunk: 125*800 = 100000 EXACTLY
#define TPC   25             // tiles per chunk = CHUNK/TR
#define NQG   2              // query groups of 512

typedef __attribute__((ext_vector_type(8))) short short8;
typedef __attribute__((ext_vector_type(4))) float f32x4;

static __device__ __forceinline__ unsigned short f2bf(float f) {
    unsigned int u = __float_as_uint(f);            // RTNE f32 -> bf16
    return (unsigned short)((u + 0x7FFFu + ((u >> 16) & 1u)) >> 16);
}
static __device__ __forceinline__ float bf2f(unsigned short h) {
    return __uint_as_float(((unsigned int)h) << 16);
}

// sorted-ascending top-K(smallest) insert, branch-guarded (rare after warmup)
__device__ __forceinline__ void topk_insert(float (&t)[K], float d) {
    if (d < t[K - 1]) {
#pragma unroll
        for (int j = K - 1; j > 0; --j)
            t[j] = (d >= t[j]) ? t[j] : ((d < t[j - 1]) ? t[j - 1] : d);
        t[0] = (d < t[0]) ? d : t[0];
    }
}

// ---- main: streaming bf16-split MFMA distances + per-chunk top-8 ----
// grid = 2 q-groups x 125 chunks = 250 blocks (1/CU); 512 thr (8 waves).
// __launch_bounds__(512, 1): CUDA semantics = min 1 block/CU -> 256-VGPR cap.
// (Round-5 lesson: (512,2) = 2 blocks/CU = 128-VGPR cap -> B-frags spilled to
// scratch, ~17kcy/tile of serialized reloads. VGPR_Count must read ~220 now.)
// Each wave: 64 queries (4 q-tiles) as -2-scaled hi/lo bf16 B-frags in regs
// (128 VGPRs). Refs stream through LDS: per tile, load f32 -> convert hi/lo
// bf16 (~110 VALU/thread, under the 931cy/SIMD MFMA shadow) -> swizzled
// ds_write. 3-term split: a.b ~= ah.bh + ah.bl + al.bh (verified absmax=0.0).
// Per (rt,s): 2KB LDS -> 12 MFMA = 96 flop/B >> 39.7 balance -> MFMA-bound.
__global__ __launch_bounds__(512, 1) void knn_mfma3(const float* __restrict__ x,
                                                    const float* __restrict__ base,
                                                    float* __restrict__ cand) {
    __shared__ unsigned short lhs[2][TR * 128];   // hi bf16, XOR slot-swizzled
    __shared__ unsigned short lls[2][TR * 128];   // lo bf16
    __shared__ float lbn[2][TR];                  // ref row norms (all rows valid)

    const int tid  = threadIdx.x;
    const int lane = tid & 63;
    const int w    = tid >> 6;          // wave 0..7
    const int lm   = lane & 15;         // operand row/col within 16
    const int kg   = lane >> 4;         // k-group 0..3
    const int qb   = blockIdx.x & 1;
    const int rc   = blockIdx.x >> 1;   // 0..124
    const int r0   = rc * CHUNK;

    // ---- B-frags: 64 queries/wave, scaled -2, split hi/lo (128 VGPRs) ----
    short8 Bh[4][4], Bl[4][4];
    float  xn[4];
#pragma unroll
    for (int qt = 0; qt < 4; ++qt) {
        const int q = qb * 512 + w * 64 + qt * 16 + lm;
        float s2 = 0.f;
#pragma unroll
        for (int s = 0; s < 4; ++s) {
            const float4 a = *(const float4*)(x + (size_t)q * D + s * 32 + kg * 8);
            const float4 b = *(const float4*)(x + (size_t)q * D + s * 32 + kg * 8 + 4);
            float v[8] = {a.x, a.y, a.z, a.w, b.x, b.y, b.z, b.w};
            short8 hh, ll;
#pragma unroll
            for (int j = 0; j < 8; ++j) {
                s2 = fmaf(v[j], v[j], s2);
                const float m2 = -2.f * v[j];            // exact (pow2 scale)
                const unsigned short h = f2bf(m2);
                const float res = m2 - bf2f(h);          // exact residual
                hh[j] = (short)h;
                ll[j] = (short)f2bf(res);
            }
            Bh[qt][s] = hh; Bl[qt][s] = ll;
        }
        s2 += __shfl_xor(s2, 16, 64);
        s2 += __shfl_xor(s2, 32, 64);
        xn[qt] = s2;
    }

    // ---- staging: thread (row srow, dim-group scol) of the 32-row tile ----
    const int srow = tid >> 4;          // 0..31
    const int scol = tid & 15;          // dims scol*8..+7

    auto convert_store = [&](const float (&v)[8], int buf) {
        float s2 = 0.f;
        short8 hh, ll;
#pragma unroll
        for (int j = 0; j < 8; ++j) {
            s2 = fmaf(v[j], v[j], s2);
            const unsigned short h = f2bf(v[j]);
            const float res = v[j] - bf2f(h);
            hh[j] = (short)h;
            ll[j] = (short)f2bf(res);
        }
        // row norm: reduce across the 16 lanes (scol) sharing this row
        s2 += __shfl_xor(s2, 1, 64);
        s2 += __shfl_xor(s2, 2, 64);
        s2 += __shfl_xor(s2, 4, 64);
        s2 += __shfl_xor(s2, 8, 64);
        const int idx = srow * 128 + 8 * (scol ^ (srow & 15));   // XOR slot swizzle
        *(short8*)&lhs[buf][idx] = hh;
        *(short8*)&lls[buf][idx] = ll;
        if (scol == 0) lbn[buf][srow] = s2;
    };

    // prologue: stage tile 0
    {
        const float* bp = base + (size_t)(r0 + srow) * D + scol * 8;
        const float4 a = *(const float4*)(bp);
        const float4 b = *(const float4*)(bp + 4);
        const float v[8] = {a.x, a.y, a.z, a.w, b.x, b.y, b.z, b.w};
        convert_store(v, 0);
    }
    __syncthreads();

    float tk[4][K];
#pragma unroll
    for (int qt = 0; qt < 4; ++qt)
#pragma unroll
        for (int j = 0; j < K; ++j) tk[qt][j] = INFINITY;

    int cur = 0;
    for (int ti = 0; ti < TPC; ++ti) {
        // prefetch next tile's f32 rows (in flight across the MFMA block)
        float pv[8];
        if (ti + 1 < TPC) {
            const float* bp = base + (size_t)(r0 + (ti + 1) * TR + srow) * D + scol * 8;
            const float4 a = *(const float4*)(bp);
            const float4 b = *(const float4*)(bp + 4);
            pv[0] = a.x; pv[1] = a.y; pv[2] = a.z; pv[3] = a.w;
            pv[4] = b.x; pv[5] = b.y; pv[6] = b.z; pv[7] = b.w;
        }

        // ---- compute on buf[cur]: 2 rt x 4 s x (4 qt x 3 terms) = 96 MFMA ----
#pragma unroll
        for (int rt = 0; rt < 2; ++rt) {
            const f32x4 bn4 = *(const f32x4*)&lbn[cur][rt * 16 + kg * 4];  // broadcast
            f32x4 acc[4];
#pragma unroll
            for (int qt = 0; qt < 4; ++qt) acc[qt] = (f32x4){0.f, 0.f, 0.f, 0.f};
#pragma unroll
            for (int s = 0; s < 4; ++s) {
                const int idx = (rt * 16 + lm) * 128 + 8 * ((s * 4 + kg) ^ lm);
                const short8 Ah = *(const short8*)&lhs[cur][idx];
                const short8 Al = *(const short8*)&lls[cur][idx];
#pragma unroll
                for (int qt = 0; qt < 4; ++qt) {
                    acc[qt] = __builtin_amdgcn_mfma_f32_16x16x32_bf16(Ah, Bh[qt][s], acc[qt], 0, 0, 0);
                    acc[qt] = __builtin_amdgcn_mfma_f32_16x16x32_bf16(Ah, Bl[qt][s], acc[qt], 0, 0, 0);
                    acc[qt] = __builtin_amdgcn_mfma_f32_16x16x32_bf16(Al, Bh[qt][s], acc[qt], 0, 0, 0);
                }
            }
#pragma unroll
            for (int qt = 0; qt < 4; ++qt)
#pragma unroll
                for (int j = 0; j < 4; ++j) topk_insert(tk[qt], acc[qt][j] + bn4[j]);
        }

        // ---- convert + store next tile into buf[cur^1] (loads landed) ----
        if (ti + 1 < TPC) convert_store(pv, cur ^ 1);
        __syncthreads();
        cur ^= 1;
    }

    // ---- merge the 4 k-group lanes holding the same query (butterfly) ----
#pragma unroll
    for (int st = 16; st <= 32; st <<= 1) {
#pragma unroll
        for (int qt = 0; qt < 4; ++qt) {
            float o[K];
#pragma unroll
            for (int j = 0; j < K; ++j) o[j] = __shfl_xor(tk[qt][j], st, 64);
#pragma unroll
            for (int j = 0; j < K; ++j) topk_insert(tk[qt], o[j]);
        }
    }

    if (kg == 0) {
#pragma unroll
        for (int qt = 0; qt < 4; ++qt) {
            const int q = qb * 512 + w * 64 + qt * 16 + lm;
            float* cp = cand + ((size_t)q * NCH + rc) * K;
#pragma unroll
            for (int j = 0; j < K; ++j)
                cp[j] = sqrtf(fmaxf(tk[qt][j] + xn[qt], 0.f));
        }
    }
}

// ---- merge 125 per-chunk top-8s per query (already sqrt'd) ----
__global__ __launch_bounds__(256, 4) void knn_merge3(const float* __restrict__ cand,
                                                     float* __restrict__ out) {
    const int q = blockIdx.x * blockDim.x + threadIdx.x;
    if (q >= NQ) return;
    const float* cp = cand + (size_t)q * (NCH * K);
    float t[K];
#pragma unroll
    for (int j = 0; j < K; ++j) t[j] = INFINITY;
    for (int i = 0; i < NCH * K; i += 4) {       // 1000 % 4 == 0
        const float4 v = *(const float4*)(cp + i);
        topk_insert(t, v.x); topk_insert(t, v.y);
        topk_insert(t, v.z); topk_insert(t, v.w);
    }
#pragma unroll
    for (int j = 0; j < K; ++j) out[(size_t)q * K + j] = t[j];
}

extern "C" void kernel_launch(void* const* d_in, const int* in_sizes, int n_in,
                              void* d_out, int out_size, void* d_ws, size_t ws_size,
                              hipStream_t stream) {
    const float* x    = (const float*)d_in[0];
    const float* base = (const float*)d_in[1];
    float* out  = (float*)d_out;
    float* cand = (float*)d_ws;    // NQ * NCH * K floats = 4 MB (small ws = small re-poison tax)

    knn_mfma3<<<NQG * NCH, 512, 0, stream>>>(x, base, cand);
    knn_merge3<<<(NQ + 255) / 256, 256, 0, stream>>>(cand, out);
}

// Round 9
// 336.844 us; speedup vs baseline: 1.1002x; 1.0337x over previous
//
#include <hip/hip_runtime.h>
#include <math.h>

#define NQ 1024
#define NR 100000
#define D  128
#define K  8
#define TR 32
#define NCH   125           // ref chunks: 125*800 = 100000 exactly
#define CHUNK 800
#define TPC   25            // tiles per chunk
#define NQG   4             // query groups of 256 (8 waves x 2 qt x 16)

typedef __attribute__((ext_vector_type(8))) short short8;
typedef __attribute__((ext_vector_type(4))) float f32x4;

static __device__ __forceinline__ unsigned short f2bf(float f) {
    unsigned int u = __float_as_uint(f);            // RTNE f32 -> bf16
    return (unsigned short)((u + 0x7FFFu + ((u >> 16) & 1u)) >> 16);
}
static __device__ __forceinline__ float bf2f(unsigned short h) {
    return __uint_as_float(((unsigned int)h) << 16);
}

// sorted-ascending top-K insert; in pass 2 gated to ~2% wave-level rate
__device__ __forceinline__ void topk_insert(float (&t)[K], float d) {
    if (d < t[K - 1]) {
#pragma unroll
        for (int j = K - 1; j > 0; --j)
            t[j] = (d >= t[j]) ? t[j] : ((d < t[j - 1]) ? t[j - 1] : d);
        t[0] = (d < t[0]) ? d : t[0];
    }
}

// ======================= PASS 1: 1-term stratified mins ======================
// Screening pass: d'1 = bn - 2*x.b with hi-bf16 ONLY (1 MFMA/term, 12.6us
// floor vs 38us 3-term). Soundness via explicit bound: bf16 products are
// EXACT in the f32 accumulator, so |d'1 - d'exact| <= 2^-6*sum|b||x| ~ 2.1
// at 6 sigma for N(0,1) data; tau margin +4.0 covers ~11 sigma.
// Per candidate: 1 add + 1 fmin (rounds 4-6's ~31-op dependent topk chain at
// ~100% wave-level taken rate was the real 180us bottleneck).
// 8 strata = (rt,j) row-classes (distinct rows after kg-merge) -> ss[rc][q][8].
// 2 qt/wave everywhere: round-4 MEASURED this shape at VGPR=88 (no spill)
// under the (512,2)=2-blocks/CU 128-VGPR cap. 4-qt needs ~200 -> spills.
__global__ __launch_bounds__(512, 2) void knn_pass1(const float* __restrict__ x,
                                                    const float* __restrict__ base,
                                                    float* __restrict__ ss) {
    __shared__ unsigned short lhs[2][TR * 128];   // hi bf16, XOR slot-swizzled
    __shared__ float lbn[2][TR];

    const int tid  = threadIdx.x;
    const int lane = tid & 63;
    const int w    = tid >> 6;
    const int lm   = lane & 15;
    const int kg   = lane >> 4;
    const int qb   = blockIdx.x & 3;
    const int rc   = blockIdx.x >> 2;       // 0..124
    const int r0   = rc * CHUNK;

    // B-frags: 32 queries/wave (2 qt), scaled -2, hi only (32 VGPRs)
    short8 Bh[2][4];
#pragma unroll
    for (int qt = 0; qt < 2; ++qt) {
        const int q = qb * 256 + w * 32 + qt * 16 + lm;
#pragma unroll
        for (int s = 0; s < 4; ++s) {
            const float4 a = *(const float4*)(x + (size_t)q * D + s * 32 + kg * 8);
            const float4 b = *(const float4*)(x + (size_t)q * D + s * 32 + kg * 8 + 4);
            float v[8] = {a.x, a.y, a.z, a.w, b.x, b.y, b.z, b.w};
            short8 hh;
#pragma unroll
            for (int j = 0; j < 8; ++j) hh[j] = (short)f2bf(-2.f * v[j]);
            Bh[qt][s] = hh;
        }
    }

    const int srow = tid >> 4;
    const int scol = tid & 15;

    auto convert_store = [&](const float (&v)[8], int buf) {
        float s2 = 0.f;
        short8 hh;
#pragma unroll
        for (int j = 0; j < 8; ++j) {
            s2 = fmaf(v[j], v[j], s2);
            hh[j] = (short)f2bf(v[j]);
        }
        s2 += __shfl_xor(s2, 1, 64);
        s2 += __shfl_xor(s2, 2, 64);
        s2 += __shfl_xor(s2, 4, 64);
        s2 += __shfl_xor(s2, 8, 64);
        const int idx = srow * 128 + 8 * (scol ^ (srow & 15));
        *(short8*)&lhs[buf][idx] = hh;
        if (scol == 0) lbn[buf][srow] = s2;
    };

    {
        const float* bp = base + (size_t)(r0 + srow) * D + scol * 8;
        const float4 a = *(const float4*)(bp);
        const float4 b = *(const float4*)(bp + 4);
        const float v[8] = {a.x, a.y, a.z, a.w, b.x, b.y, b.z, b.w};
        convert_store(v, 0);
    }
    __syncthreads();

    float sl[2][8];
#pragma unroll
    for (int qt = 0; qt < 2; ++qt)
#pragma unroll
        for (int j = 0; j < 8; ++j) sl[qt][j] = INFINITY;

    int cur = 0;
    for (int ti = 0; ti < TPC; ++ti) {
        float pv[8];
        if (ti + 1 < TPC) {
            const float* bp = base + (size_t)(r0 + (ti + 1) * TR + srow) * D + scol * 8;
            const float4 a = *(const float4*)(bp);
            const float4 b = *(const float4*)(bp + 4);
            pv[0] = a.x; pv[1] = a.y; pv[2] = a.z; pv[3] = a.w;
            pv[4] = b.x; pv[5] = b.y; pv[6] = b.z; pv[7] = b.w;
        }

#pragma unroll
        for (int rt = 0; rt < 2; ++rt) {
            const f32x4 bn4 = *(const f32x4*)&lbn[cur][rt * 16 + kg * 4];
            f32x4 acc[2];
#pragma unroll
            for (int qt = 0; qt < 2; ++qt) acc[qt] = (f32x4){0.f, 0.f, 0.f, 0.f};
#pragma unroll
            for (int s = 0; s < 4; ++s) {
                const int idx = (rt * 16 + lm) * 128 + 8 * ((s * 4 + kg) ^ lm);
                const short8 Ah = *(const short8*)&lhs[cur][idx];
#pragma unroll
                for (int qt = 0; qt < 2; ++qt)
                    acc[qt] = __builtin_amdgcn_mfma_f32_16x16x32_bf16(Ah, Bh[qt][s], acc[qt], 0, 0, 0);
            }
#pragma unroll
            for (int qt = 0; qt < 2; ++qt)
#pragma unroll
                for (int j = 0; j < 4; ++j)
                    sl[qt][rt * 4 + j] = fminf(sl[qt][rt * 4 + j], acc[qt][j] + bn4[j]);
        }

        if (ti + 1 < TPC) convert_store(pv, cur ^ 1);
        __syncthreads();
        cur ^= 1;
    }

    // kg-merge strata (fmin across the 4 lanes sharing each query)
#pragma unroll
    for (int qt = 0; qt < 2; ++qt)
#pragma unroll
        for (int j = 0; j < 8; ++j) {
            sl[qt][j] = fminf(sl[qt][j], __shfl_xor(sl[qt][j], 16, 64));
            sl[qt][j] = fminf(sl[qt][j], __shfl_xor(sl[qt][j], 32, 64));
        }

    if (kg == 0) {
#pragma unroll
        for (int qt = 0; qt < 2; ++qt) {
            const int q = qb * 256 + w * 32 + qt * 16 + lm;
            float* sp = ss + ((size_t)rc * NQ + q) * 8;
            *(f32x4*)(sp)     = (f32x4){sl[qt][0], sl[qt][1], sl[qt][2], sl[qt][3]};
            *(f32x4*)(sp + 4) = (f32x4){sl[qt][4], sl[qt][5], sl[qt][6], sl[qt][7]};
        }
    }
}

// ======================= TAU: per-query filter threshold =====================
// tau_raw = max of 8 distinct rows' 1-term d' >= d'_8(1-term). Every true
// top-8 row has d'_3term <= tau_raw + 2.11; +4.0 margin covers ~11 sigma.
__global__ __launch_bounds__(256, 4) void knn_tau(const float* __restrict__ ss,
                                                  float* __restrict__ tau) {
    const int q = blockIdx.x * 256 + threadIdx.x;
    f32x4 m0 = {INFINITY, INFINITY, INFINITY, INFINITY};
    f32x4 m1 = m0;
    for (int rc = 0; rc < NCH; ++rc) {
        const float* sp = ss + ((size_t)rc * NQ + q) * 8;
        const f32x4 a = *(const f32x4*)(sp);
        const f32x4 b = *(const f32x4*)(sp + 4);
#pragma unroll
        for (int j = 0; j < 4; ++j) { m0[j] = fminf(m0[j], a[j]); m1[j] = fminf(m1[j], b[j]); }
    }
    float t = m0[0];
#pragma unroll
    for (int j = 1; j < 4; ++j) t = fmaxf(t, m0[j]);
#pragma unroll
    for (int j = 0; j < 4; ++j) t = fmaxf(t, m1[j]);
    tau[q] = t + 4.0f;
}

// ======================= PASS 2: filtered exact top-8 ========================
// Full 3-term split (verified absmax=0.0 rounds 4-6); insert only when
// d <= tau[q] -> wave-level insert rate ~2%: the topk chain cost vanishes.
__global__ __launch_bounds__(512, 2) void knn_pass2(const float* __restrict__ x,
                                                    const float* __restrict__ base,
                                                    const float* __restrict__ tau,
                                                    float* __restrict__ cand) {
    __shared__ unsigned short lhs[2][TR * 128];
    __shared__ unsigned short lls[2][TR * 128];
    __shared__ float lbn[2][TR];

    const int tid  = threadIdx.x;
    const int lane = tid & 63;
    const int w    = tid >> 6;
    const int lm   = lane & 15;
    const int kg   = lane >> 4;
    const int qb   = blockIdx.x & 3;
    const int rc   = blockIdx.x >> 2;
    const int r0   = rc * CHUNK;

    short8 Bh[2][4], Bl[2][4];
    float  xn[2], tau2[2];
#pragma unroll
    for (int qt = 0; qt < 2; ++qt) {
        const int q = qb * 256 + w * 32 + qt * 16 + lm;
        tau2[qt] = tau[q];
        float s2 = 0.f;
#pragma unroll
        for (int s = 0; s < 4; ++s) {
            const float4 a = *(const float4*)(x + (size_t)q * D + s * 32 + kg * 8);
            const float4 b = *(const float4*)(x + (size_t)q * D + s * 32 + kg * 8 + 4);
            float v[8] = {a.x, a.y, a.z, a.w, b.x, b.y, b.z, b.w};
            short8 hh, ll;
#pragma unroll
            for (int j = 0; j < 8; ++j) {
                s2 = fmaf(v[j], v[j], s2);
                const float m2 = -2.f * v[j];
                const unsigned short h = f2bf(m2);
                const float res = m2 - bf2f(h);
                hh[j] = (short)h;
                ll[j] = (short)f2bf(res);
            }
            Bh[qt][s] = hh; Bl[qt][s] = ll;
        }
        s2 += __shfl_xor(s2, 16, 64);
        s2 += __shfl_xor(s2, 32, 64);
        xn[qt] = s2;
    }

    const int srow = tid >> 4;
    const int scol = tid & 15;

    auto convert_store = [&](const float (&v)[8], int buf) {
        float s2 = 0.f;
        short8 hh, ll;
#pragma unroll
        for (int j = 0; j < 8; ++j) {
            s2 = fmaf(v[j], v[j], s2);
            const unsigned short h = f2bf(v[j]);
            const float res = v[j] - bf2f(h);
            hh[j] = (short)h;
            ll[j] = (short)f2bf(res);
        }
        s2 += __shfl_xor(s2, 1, 64);
        s2 += __shfl_xor(s2, 2, 64);
        s2 += __shfl_xor(s2, 4, 64);
        s2 += __shfl_xor(s2, 8, 64);
        const int idx = srow * 128 + 8 * (scol ^ (srow & 15));
        *(short8*)&lhs[buf][idx] = hh;
        *(short8*)&lls[buf][idx] = ll;
        if (scol == 0) lbn[buf][srow] = s2;
    };

    {
        const float* bp = base + (size_t)(r0 + srow) * D + scol * 8;
        const float4 a = *(const float4*)(bp);
        const float4 b = *(const float4*)(bp + 4);
        const float v[8] = {a.x, a.y, a.z, a.w, b.x, b.y, b.z, b.w};
        convert_store(v, 0);
    }
    __syncthreads();

    float tk[2][K];
#pragma unroll
    for (int qt = 0; qt < 2; ++qt)
#pragma unroll
        for (int j = 0; j < K; ++j) tk[qt][j] = INFINITY;

    int cur = 0;
    for (int ti = 0; ti < TPC; ++ti) {
        float pv[8];
        if (ti + 1 < TPC) {
            const float* bp = base + (size_t)(r0 + (ti + 1) * TR + srow) * D + scol * 8;
            const float4 a = *(const float4*)(bp);
            const float4 b = *(const float4*)(bp + 4);
            pv[0] = a.x; pv[1] = a.y; pv[2] = a.z; pv[3] = a.w;
            pv[4] = b.x; pv[5] = b.y; pv[6] = b.z; pv[7] = b.w;
        }

#pragma unroll
        for (int rt = 0; rt < 2; ++rt) {
            const f32x4 bn4 = *(const f32x4*)&lbn[cur][rt * 16 + kg * 4];
            f32x4 acc[2];
#pragma unroll
            for (int qt = 0; qt < 2; ++qt) acc[qt] = (f32x4){0.f, 0.f, 0.f, 0.f};
#pragma unroll
            for (int s = 0; s < 4; ++s) {
                const int idx = (rt * 16 + lm) * 128 + 8 * ((s * 4 + kg) ^ lm);
                const short8 Ah = *(const short8*)&lhs[cur][idx];
                const short8 Al = *(const short8*)&lls[cur][idx];
#pragma unroll
                for (int qt = 0; qt < 2; ++qt) {
                    acc[qt] = __builtin_amdgcn_mfma_f32_16x16x32_bf16(Ah, Bh[qt][s], acc[qt], 0, 0, 0);
                    acc[qt] = __builtin_amdgcn_mfma_f32_16x16x32_bf16(Ah, Bl[qt][s], acc[qt], 0, 0, 0);
                    acc[qt] = __builtin_amdgcn_mfma_f32_16x16x32_bf16(Al, Bh[qt][s], acc[qt], 0, 0, 0);
                }
            }
#pragma unroll
            for (int qt = 0; qt < 2; ++qt)
#pragma unroll
                for (int j = 0; j < 4; ++j) {
                    const float d = acc[qt][j] + bn4[j];
                    if (d <= tau2[qt]) topk_insert(tk[qt], d);
                }
        }

        if (ti + 1 < TPC) convert_store(pv, cur ^ 1);
        __syncthreads();
        cur ^= 1;
    }

    // merge the 4 kg lanes per query (lists are mostly INF -> cheap)
#pragma unroll
    for (int st = 16; st <= 32; st <<= 1) {
#pragma unroll
        for (int qt = 0; qt < 2; ++qt) {
            float o[K];
#pragma unroll
            for (int j = 0; j < K; ++j) o[j] = __shfl_xor(tk[qt][j], st, 64);
#pragma unroll
            for (int j = 0; j < K; ++j) topk_insert(tk[qt], o[j]);
        }
    }

    if (kg == 0) {
#pragma unroll
        for (int qt = 0; qt < 2; ++qt) {
            const int q = qb * 256 + w * 32 + qt * 16 + lm;
            float* cp = cand + ((size_t)q * NCH + rc) * K;
#pragma unroll
            for (int j = 0; j < K; ++j)
                cp[j] = sqrtf(fmaxf(tk[qt][j] + xn[qt], 0.f));
        }
    }
}

// ======================= merge per-chunk top-8s ==============================
__global__ __launch_bounds__(256, 4) void knn_merge(const float* __restrict__ cand,
                                                    float* __restrict__ out) {
    const int q = blockIdx.x * blockDim.x + threadIdx.x;
    if (q >= NQ) return;
    const float* cp = cand + (size_t)q * (NCH * K);
    float t[K];
#pragma unroll
    for (int j = 0; j < K; ++j) t[j] = INFINITY;
    for (int i = 0; i < NCH * K; i += 4) {
        const float4 v = *(const float4*)(cp + i);
        topk_insert(t, v.x); topk_insert(t, v.y);
        topk_insert(t, v.z); topk_insert(t, v.w);
    }
#pragma unroll
    for (int j = 0; j < K; ++j) out[(size_t)q * K + j] = t[j];
}

extern "C" void kernel_launch(void* const* d_in, const int* in_sizes, int n_in,
                              void* d_out, int out_size, void* d_ws, size_t ws_size,
                              hipStream_t stream) {
    const float* x    = (const float*)d_in[0];
    const float* base = (const float*)d_in[1];
    float* out = (float*)d_out;

    // ws: ss[125][1024][8] 4.096MB | tau[1024] 4KB | cand[1024][125][8] 4.096MB
    const size_t OFF_TAU  = (size_t)NCH * NQ * 8 * 4;          // 4,096,000
    const size_t OFF_CAND = OFF_TAU + 4096;
    float* ss   = (float*)d_ws;
    float* tau  = (float*)((char*)d_ws + OFF_TAU);
    float* cand = (float*)((char*)d_ws + OFF_CAND);

    knn_pass1<<<NQG * NCH, 512, 0, stream>>>(x, base, ss);
    knn_tau<<<NQ / 256, 256, 0, stream>>>(ss, tau);
    knn_pass2<<<NQG * NCH, 512, 0, stream>>>(x, base, tau, cand);
    knn_merge<<<(NQ + 255) / 256, 256, 0, stream>>>(cand, out);
}